// Round 14
// baseline (273.227 us; speedup 1.0000x reference)
//
#include <hip/hip_runtime.h>

typedef unsigned int u32;
typedef unsigned short u16;
typedef __attribute__((ext_vector_type(8))) short bf16x8;
typedef __attribute__((ext_vector_type(4))) float f32x4;

constexpr int BATCH = 32;
constexpr int DIM   = 256;
constexpr int NPTS  = 512;
constexpr int NH    = 8;
constexpr int KD    = 16;
constexpr int DHEAD = 64;
constexpr int NH_KD = 128;
constexpr int DH    = 512;

__device__ __forceinline__ float bflo(u32 u){ return __uint_as_float(u << 16); }
__device__ __forceinline__ float bfhi(u32 u){ return __uint_as_float(u & 0xffff0000u); }
__device__ __forceinline__ float bf2f(u16 u){ return __uint_as_float(((u32)u) << 16); }

// HW packed f32->bf16 (RNE).
__device__ __forceinline__ u32 pack2bf(float a, float b){
  u32 r;
  asm("v_cvt_pk_bf16_f32 %0, %1, %2" : "=v"(r) : "v"(a), "v"(b));
  return r;
}
__device__ __forceinline__ u16 f2bf(float f){ return (u16)pack2bf(f, f); }

union B8 { bf16x8 v; uint2 u2[2]; uint4 u4; };

// async global->LDS, 16B per lane. LDS dst wave-uniform; HW writes dst+lane*16.
typedef const __attribute__((address_space(1))) unsigned int gu32_t;
typedef __attribute__((address_space(3))) unsigned int su32_t;
__device__ __forceinline__ void gld16(const u16* src, u16* ldsDst){
  __builtin_amdgcn_global_load_lds((gu32_t*)src, (su32_t*)ldsDst, 16, 0, 0);
}

// 4x4 transpose across a lane quad (bf16-output epilogues only).
__device__ __forceinline__ void quadtr(float v[4], int lq){
  float t[4], y[4];
  #pragma unroll
  for (int r = 0; r < 4; r++) t[r] = __shfl_xor(v[r], 1, 64);
  #pragma unroll
  for (int r = 0; r < 4; r++) y[r] = ((r & 1) == (lq & 1)) ? v[r] : t[r ^ 1];
  #pragma unroll
  for (int r = 0; r < 4; r++) t[r] = __shfl_xor(y[r], 2, 64);
  #pragma unroll
  for (int r = 0; r < 4; r++) v[r] = ((r & 2) == (lq & 2)) ? y[r] : t[r ^ 2];
}

// ---------------------------------------------------------------------------
// K_pre: fused preprocessing (all independent, disjoint outputs):
//   blk [0,640)      : weight scale-fold + bf16 cast
//   blk [640,1664)   : x transpose fp32->bf16 rows
//   blk [1664,2688)  : bias table bf16 S^T C-layout, pre-scaled log2e.
// ---------------------------------------------------------------------------
__global__ __launch_bounds__(256) void k_pre(
    const float* __restrict__ wq, const float* __restrict__ sq,
    const float* __restrict__ wp, const float* __restrict__ sp,
    u32* __restrict__ wqb, u32* __restrict__ pwb,
    const float* __restrict__ x, u16* __restrict__ xbt,
    const float* __restrict__ ab, const int* __restrict__ bidx,
    u32* __restrict__ biasb)
{
  __shared__ u16 T[64*68];
  const int blk = blockIdx.x;
  const int tid = threadIdx.x;

  if (blk < 640){
    int t = blk * 256 + tid;
    if (t < 98304){                      // 768*256/2
      int i = 2*t;
      float s = sq[i >> 8];
      wqb[t] = pack2bf(wq[i]*s, wq[i+1]*s);
    } else {
      int j = t - 98304;                 // 256*512/2
      int i = 2*j;
      float s = sp[i >> 9];
      pwb[j] = pack2bf(wp[i]*s, wp[i+1]*s);
    }
  } else if (blk < 1664){
    const int bk = blk - 640;
    const int b = bk >> 5, ct = (bk >> 3) & 3, nt = bk & 7;
    const int c0 = ct*64, n0 = nt*64;

    const float* xb = x + ((size_t)b*DIM + c0)*NPTS + n0;
    #pragma unroll
    for (int it = 0; it < 4; it++){
      int cc = (tid >> 4) + it*16;
      int nn = (tid & 15) * 4;
      float4 v = *(const float4*)(xb + (size_t)cc*NPTS + nn);
      u32* dst = (u32*)&T[cc*68 + nn];
      dst[0] = pack2bf(v.x, v.y);
      dst[1] = pack2bf(v.z, v.w);
    }
    __syncthreads();
    u16* ob = xbt + ((size_t)b*NPTS + n0)*DIM + c0;
    #pragma unroll
    for (int it = 0; it < 4; it++){
      int nn = (tid >> 4) + it*16;
      int cc = (tid & 15) * 4;
      uint2 w;
      w.x = (u32)T[(cc+0)*68 + nn] | ((u32)T[(cc+1)*68 + nn] << 16);
      w.y = (u32)T[(cc+2)*68 + nn] | ((u32)T[(cc+3)*68 + nn] << 16);
      *(uint2*)(ob + (size_t)nn*DIM + cc) = w;
    }
  } else {
    const float L2E = 1.4426950408889634f;
    const int bk = blk - 1664;
    const int mtg = bk >> 5, ntile = bk & 31;
    const int lane = tid & 63;
    const int h0 = tid >> 6;
    const int qq = lane >> 4;
    const int n = ntile*16 + (lane & 15);
    int idx[4];
    #pragma unroll
    for (int r = 0; r < 4; r++)
      idx[r] = bidx[(size_t)n*NPTS + mtg*16 + qq*4 + r];
    for (int h = h0; h < NH; h += 4){
      float v0 = ab[h*NPTS + idx[0]] * L2E, v1 = ab[h*NPTS + idx[1]] * L2E;
      float v2 = ab[h*NPTS + idx[2]] * L2E, v3 = ab[h*NPTS + idx[3]] * L2E;
      u32* dst = biasb + (((size_t)(h*32 + mtg)*32 + ntile)*64 + lane)*2;
      dst[0] = pack2bf(v0, v1);
      dst[1] = pack2bf(v2, v3);
    }
  }
}

// ---------------------------------------------------------------------------
// K1: qkv MFMA GEMM (R12-proven): LDS 2-phase pipeline, 128x64 tiles,
// 1536 blocks = 6 blocks/CU, XCD swizzle, packed bf16 epilogue.
// ---------------------------------------------------------------------------
__global__ __launch_bounds__(256) void k_qkv(
    const u16* __restrict__ xbt, const u16* __restrict__ wqb,
    const float* __restrict__ bias,
    u16* __restrict__ qfb, u16* __restrict__ kb, u16* __restrict__ vb)
{
  __shared__ u16 As[2][4096];          // 128 rows x 32 cols
  __shared__ u16 Bs[2][2048];          //  64 rows x 32 cols

  const int blk = blockIdx.x;          // 1536 blocks, XCD-swizzled
  const int xcd = blk & 7;
  const int idx = blk >> 3;            // 0..191
  const int pair = xcd*32 + idx/6;     // 0..255 = (b,Nblk) panel
  const int Mblk = idx % 6;
  const int Nblk = pair & 7;
  const int b    = pair >> 3;

  const int tid = threadIdx.x, wave = tid >> 6, lane = tid & 63;
  const int wm = wave >> 1, wn = wave & 1;
  const int c = lane & 15, q = lane >> 4;
  const int lq = lane & 3;
  const int Mbase = Mblk*128 + wm*64;
  const int Nbase = Nblk*64 + wn*32;

  f32x4 acc[4][2];
  #pragma unroll
  for (int mt = 0; mt < 4; mt++){
    f32x4 bi;
    #pragma unroll
    for (int r = 0; r < 4; r++) bi[r] = bias[Mbase + mt*16 + q*4 + r];
    #pragma unroll
    for (int nt = 0; nt < 2; nt++) acc[mt][nt] = bi;
  }

  const u16* aT = wqb + (size_t)(Mblk*128)*DIM;
  const u16* bT = xbt + ((size_t)b*NPTS + Nblk*64)*DIM;

  const int srow = lane >> 2, scol = (lane & 3)*8;

  auto STAGE = [&](int buf, int kc){
    #pragma unroll
    for (int i = 0; i < 2; i++){
      const int ch = wave*2 + i;       // A: 8 chunks of 16 rows
      gld16(aT + (size_t)(ch*16 + srow)*DIM + kc + scol, &As[buf][ch*512]);
    }
    // B: 4 chunks of 16 rows, one per wave
    gld16(bT + (size_t)(wave*16 + srow)*DIM + kc + scol, &Bs[buf][wave*512]);
  };

  STAGE(0, 0);
  __syncthreads();

  int cur = 0;
  #pragma unroll 2
  for (int ks = 0; ks < 8; ks++){      // K=256, BK=32
    if (ks < 7) STAGE(cur^1, (ks+1)*32);
    bf16x8 aW[4], bX[2];
    #pragma unroll
    for (int mt = 0; mt < 4; mt++)
      aW[mt] = *(const bf16x8*)&As[cur][(wm*64 + mt*16 + c)*32 + q*8];
    #pragma unroll
    for (int nt = 0; nt < 2; nt++)
      bX[nt] = *(const bf16x8*)&Bs[cur][(wn*32 + nt*16 + c)*32 + q*8];
    #pragma unroll
    for (int mt = 0; mt < 4; mt++)
      #pragma unroll
      for (int nt = 0; nt < 2; nt++)
        acc[mt][nt] = __builtin_amdgcn_mfma_f32_16x16x32_bf16(
            aW[mt], bX[nt], acc[mt][nt], 0, 0, 0);
    __syncthreads();
    cur ^= 1;
  }

  #pragma unroll
  for (int mt = 0; mt < 4; mt++){
    const int m0 = wm*64 + mt*16 + q*4;          // local m row-group base
    #pragma unroll
    for (int nt = 0; nt < 2; nt++){
      if (Mblk == 1){
        // kb[(bh)*512 + n][16ch]: 4 values are channel-contiguous -> pack.
        const int n = Nbase + nt*16 + c;
        const int hh = wm*4 + mt;
        uint2 w;
        w.x = pack2bf(acc[mt][nt][0], acc[mt][nt][1]);
        w.y = pack2bf(acc[mt][nt][2], acc[mt][nt][3]);
        *(uint2*)(kb + (((size_t)b*NH + hh)*NPTS + n)*16 + q*4) = w;
      } else {
        // transpose to n-contig, then 8B store.
        float v[4];
        #pragma unroll
        for (int r = 0; r < 4; r++) v[r] = acc[mt][nt][r];
        quadtr(v, lq);
        const int nq = Nbase + nt*16 + (c & ~3);  // n quad base (mult of 4)
        uint2 w;
        w.x = pack2bf(v[0], v[1]);
        w.y = pack2bf(v[2], v[3]);
        if (Mblk == 0){
          *(uint2*)(qfb + ((size_t)b*NH_KD + m0 + lq)*NPTS + nq) = w;
        } else {
          const int d = (Mblk - 2)*128 + m0 + lq;
          const int pb = (nq & ~31) | (((nq >> 4) & 1) << 2) | (((nq >> 2) & 3) << 3);
          *(uint2*)(vb + ((size_t)b*DH + d)*NPTS + pb) = w;
        }
      }
    }
  }
}

// ---------------------------------------------------------------------------
// K3: MFMA flash attention + fused depthwise conv. R14: KVBLK widened 32->64
// (windows 16->8). Sync skeleton UNCHANGED from the proven R10/R13 form:
// V stage load at window top, ds_write at bottom before the single barrier;
// K+bias one-window-ahead register prefetch; exp2; HW cvt_pk; setprio (R13).
// Per window now 24 MFMA vs 12 -> per-window overhead (barrier/backedge/
// addressing) amortized 2x. vb's m-permutation is within 32-blocks, so the
// two 32-chunks per window (g01->aPa*VL, g23->aPb*VH) keep the exact pack
// layout; exp/ls/O accumulation sequences unchanged -> bit-identical output.
// LDS 22.5KB/block (still 4 blocks/CU).
// ---------------------------------------------------------------------------
__global__ __launch_bounds__(256, 4) void k_attn(
    const u16* __restrict__ qfb, const u16* __restrict__ kb,
    const u16* __restrict__ vb, const u16* __restrict__ biasb,
    const float* __restrict__ dww, const float* __restrict__ dws,
    const float* __restrict__ dwb,
    u16* __restrict__ attnout)
{
  __shared__ u16 VS[2][64][72];          // [buf][d row][64 m + 8 pad]
  __shared__ u16 QS[128][16];            // conv output: [pt_local][head-ch]

  const int hb = blockIdx.x, tg = blockIdx.y;
  const int b = hb >> 3, h = hb & 7;
  const int tid = threadIdx.x;
  const int lane = tid & 63, wave = tid >> 6;
  const int c = lane & 15, q = lane >> 4;
  const int bh = b*NH + h;
  const int nt0 = tg*8 + wave*2;        // ntiles {nt0, nt0+1}
  const int n0 = nt0*16;

  // V staging: 256 threads x 2 x 16B covers the 64x64 bf16 tile.
  const int vr = tid >> 3;              // d row 0..31 (+32 for second half)
  const int vc = (tid & 7) * 8;         // m col 0..56

  const u16* kbh = kb + ((size_t)bh*NPTS)*16;
  const u16* vbh = vb + ((size_t)b*DH + h*DHEAD)*NPTS;
  const u16* bw0 = biasb + (size_t)h*262144 + (size_t)nt0*256 + lane*4;

  // ---- prologue part 1: issue window-0 V stage loads (hide under conv).
  bf16x8 sva0 = *(const bf16x8*)(vbh + (size_t)vr*NPTS + vc);
  bf16x8 svb0 = *(const bf16x8*)(vbh + (size_t)(vr+32)*NPTS + vc);

  // ---- fused depthwise conv (unchanged from R10).
  {
    const int row = tid >> 4;           // 0..15 = rz*8 + ry
    const int rz  = row >> 3, ry = row & 7;
    const int chl = tid & 15;
    const int qch = h*16 + chl;
    const int z0  = tg*2;

    float wv[27];
    #pragma unroll
    for (int i = 0; i < 27; i++) wv[i] = dww[qch*27 + i];
    const float sc = dws[qch], bi = dwb[qch];
    const u16* qrow = qfb + ((size_t)b*NH_KD + qch)*NPTS;

    float acc8[8];
    #pragma unroll
    for (int xo = 0; xo < 8; xo++) acc8[xo] = 0.f;

    #pragma unroll
    for (int dz = 0; dz < 3; dz++){
      int zz = z0 + rz + dz - 1; if ((unsigned)zz > 7u) continue;
      #pragma unroll
      for (int dy = 0; dy < 3; dy++){
        int yy = ry + dy - 1; if ((unsigned)yy > 7u) continue;
        B8 rvb; rvb.v = *(const bf16x8*)(qrow + zz*64 + yy*8);
        float r[8];
        #pragma unroll
        for (int xo = 0; xo < 8; xo++) r[xo] = bf2f(((const u16*)&rvb)[xo]);
        #pragma unroll
        for (int dx = 0; dx < 3; dx++){
          float w = wv[dz*9 + dy*3 + dx];
          #pragma unroll
          for (int xo = 0; xo < 8; xo++){
            int xx = xo + dx - 1;
            if (xx >= 0 && xx < 8) acc8[xo] += r[xx]*w;
          }
        }
      }
    }
    // fold 1/sqrt(KD)=0.25 and log2(e) (exp -> exp2 below).
    #pragma unroll
    for (int xo = 0; xo < 8; xo++){
      float v = (acc8[xo]*sc + bi) * 0.36067376022224085f;
      QS[row*8 + xo][chl] = f2bf(v);
    }
  }

  // ---- prologue part 2: V(0) LDS write + window-0 K/bias prefetch.
  *(bf16x8*)&VS[0][vr][vc]    = sva0;
  *(bf16x8*)&VS[0][vr+32][vc] = svb0;

  const bf16x8 zfrag = {0,0,0,0,0,0,0,0};
  bf16x8 aK[4];
  uint2 u0[4], u1[4];

  auto loadKB = [&](int win, bf16x8 k[4], uint2 x0[4], uint2 x1[4]){
    const int mtg = win*4;
    #pragma unroll
    for (int g = 0; g < 4; g++){
      if (q < 2)
        k[g] = *(const bf16x8*)(kbh + (((size_t)(win*64 + g*16 + c)) << 4) + q*8);
      else
        k[g] = zfrag;
      x0[g] = *(const uint2*)(bw0 + (size_t)(mtg+g)*8192);
      x1[g] = *(const uint2*)(bw0 + 256 + (size_t)(mtg+g)*8192);
    }
  };

  loadKB(0, aK, u0, u1);
  __syncthreads();

  // ---- Q fragments from the conv LDS tile (one-time).
  bf16x8 bQ0 = zfrag, bQ1 = zfrag;
  if (q < 2){
    bQ0 = *(const bf16x8*)&QS[wave*32 + c][q*8];
    bQ1 = *(const bf16x8*)&QS[wave*32 + 16 + c][q*8];
  }

  f32x4 O0[4] = {{0,0,0,0},{0,0,0,0},{0,0,0,0},{0,0,0,0}};
  f32x4 O1[4] = {{0,0,0,0},{0,0,0,0},{0,0,0,0},{0,0,0,0}};
  float ls0 = 0.f, ls1 = 0.f;

  #pragma unroll 1
  for (int win = 0; win < 8; win++){
    // issue next window's V stage loads early (write deferred to bottom)
    const int wnext = (win < 7) ? win + 1 : 7;
    bf16x8 sva = *(const bf16x8*)(vbh + (size_t)vr*NPTS + wnext*64 + vc);
    bf16x8 svb = *(const bf16x8*)(vbh + (size_t)(vr+32)*NPTS + wnext*64 + vc);

    bf16x8 nK[4];
    uint2 m0[4], m1[4];
    if (win < 7)
      loadKB(win+1, nK, m0, m1);

    // V fragments from LDS: low chunk (m 0..31) and high chunk (m 32..63)
    const int vbuf = win & 1;
    bf16x8 VL[4], VH[4];
    #pragma unroll
    for (int dt = 0; dt < 4; dt++){
      VL[dt] = *(const bf16x8*)&VS[vbuf][dt*16 + c][q*8];
      VH[dt] = *(const bf16x8*)&VS[vbuf][dt*16 + c][32 + q*8];
    }

    // S-MFMAs: 2 ntiles x 4 m-groups
    f32x4 S0[4], S1[4];
    __builtin_amdgcn_s_setprio(1);
    #pragma unroll
    for (int g = 0; g < 4; g++){
      f32x4 c0, c1;
      c0[0]=bflo(u0[g].x); c0[1]=bfhi(u0[g].x); c0[2]=bflo(u0[g].y); c0[3]=bfhi(u0[g].y);
      c1[0]=bflo(u1[g].x); c1[1]=bfhi(u1[g].x); c1[2]=bflo(u1[g].y); c1[3]=bfhi(u1[g].y);
      S0[g] = __builtin_amdgcn_mfma_f32_16x16x32_bf16(aK[g], bQ0, c0, 0, 0, 0);
      S1[g] = __builtin_amdgcn_mfma_f32_16x16x32_bf16(aK[g], bQ1, c1, 0, 0, 0);
    }
    __builtin_amdgcn_s_setprio(0);

    // exp + pack: chunk a = groups 0,1 (m 0..31); chunk b = groups 2,3.
    float e0, e1, e2, e3;
    B8 aP0a, aP0b, aP1a, aP1b;
    e0 = __builtin_amdgcn_exp2f(S0[0][0]); e1 = __builtin_amdgcn_exp2f(S0[0][1]);
    e2 = __builtin_amdgcn_exp2f(S0[0][2]); e3 = __builtin_amdgcn_exp2f(S0[0][3]);
    ls0 += (e0 + e1) + (e2 + e3);
    aP0a.u4.x = pack2bf(e0, e1); aP0a.u4.y = pack2bf(e2, e3);
    e0 = __builtin_amdgcn_exp2f(S0[1][0]); e1 = __builtin_amdgcn_exp2f(S0[1][1]);
    e2 = __builtin_amdgcn_exp2f(S0[1][2]); e3 = __builtin_amdgcn_exp2f(S0[1][3]);
    ls0 += (e0 + e1) + (e2 + e3);
    aP0a.u4.z = pack2bf(e0, e1); aP0a.u4.w = pack2bf(e2, e3);
    e0 = __builtin_amdgcn_exp2f(S0[2][0]); e1 = __builtin_amdgcn_exp2f(S0[2][1]);
    e2 = __builtin_amdgcn_exp2f(S0[2][2]); e3 = __builtin_amdgcn_exp2f(S0[2][3]);
    ls0 += (e0 + e1) + (e2 + e3);
    aP0b.u4.x = pack2bf(e0, e1); aP0b.u4.y = pack2bf(e2, e3);
    e0 = __builtin_amdgcn_exp2f(S0[3][0]); e1 = __builtin_amdgcn_exp2f(S0[3][1]);
    e2 = __builtin_amdgcn_exp2f(S0[3][2]); e3 = __builtin_amdgcn_exp2f(S0[3][3]);
    ls0 += (e0 + e1) + (e2 + e3);
    aP0b.u4.z = pack2bf(e0, e1); aP0b.u4.w = pack2bf(e2, e3);

    e0 = __builtin_amdgcn_exp2f(S1[0][0]); e1 = __builtin_amdgcn_exp2f(S1[0][1]);
    e2 = __builtin_amdgcn_exp2f(S1[0][2]); e3 = __builtin_amdgcn_exp2f(S1[0][3]);
    ls1 += (e0 + e1) + (e2 + e3);
    aP1a.u4.x = pack2bf(e0, e1); aP1a.u4.y = pack2bf(e2, e3);
    e0 = __builtin_amdgcn_exp2f(S1[1][0]); e1 = __builtin_amdgcn_exp2f(S1[1][1]);
    e2 = __builtin_amdgcn_exp2f(S1[1][2]); e3 = __builtin_amdgcn_exp2f(S1[1][3]);
    ls1 += (e0 + e1) + (e2 + e3);
    aP1a.u4.z = pack2bf(e0, e1); aP1a.u4.w = pack2bf(e2, e3);
    e0 = __builtin_amdgcn_exp2f(S1[2][0]); e1 = __builtin_amdgcn_exp2f(S1[2][1]);
    e2 = __builtin_amdgcn_exp2f(S1[2][2]); e3 = __builtin_amdgcn_exp2f(S1[2][3]);
    ls1 += (e0 + e1) + (e2 + e3);
    aP1b.u4.x = pack2bf(e0, e1); aP1b.u4.y = pack2bf(e2, e3);
    e0 = __builtin_amdgcn_exp2f(S1[3][0]); e1 = __builtin_amdgcn_exp2f(S1[3][1]);
    e2 = __builtin_amdgcn_exp2f(S1[3][2]); e3 = __builtin_amdgcn_exp2f(S1[3][3]);
    ls1 += (e0 + e1) + (e2 + e3);
    aP1b.u4.z = pack2bf(e0, e1); aP1b.u4.w = pack2bf(e2, e3);

    __builtin_amdgcn_s_setprio(1);
    #pragma unroll
    for (int dt = 0; dt < 4; dt++){
      O0[dt] = __builtin_amdgcn_mfma_f32_16x16x32_bf16(aP0a.v, VL[dt], O0[dt], 0, 0, 0);
      O0[dt] = __builtin_amdgcn_mfma_f32_16x16x32_bf16(aP0b.v, VH[dt], O0[dt], 0, 0, 0);
      O1[dt] = __builtin_amdgcn_mfma_f32_16x16x32_bf16(aP1a.v, VL[dt], O1[dt], 0, 0, 0);
      O1[dt] = __builtin_amdgcn_mfma_f32_16x16x32_bf16(aP1b.v, VH[dt], O1[dt], 0, 0, 0);
    }
    __builtin_amdgcn_s_setprio(0);

    // write next window's V tile to the other buffer, then sync.
    if (win < 7){
      *(bf16x8*)&VS[wnext & 1][vr][vc]    = sva;
      *(bf16x8*)&VS[wnext & 1][vr+32][vc] = svb;
    }
    __syncthreads();

    #pragma unroll
    for (int g = 0; g < 4; g++){
      aK[g] = nK[g]; u0[g] = m0[g]; u1[g] = m1[g];
    }
  }

  ls0 += __shfl_xor(ls0, 16, 64);
  ls0 += __shfl_xor(ls0, 32, 64);
  ls1 += __shfl_xor(ls1, 16, 64);
  ls1 += __shfl_xor(ls1, 32, 64);
  f32x4 inv0, inv1;
  #pragma unroll
  for (int r = 0; r < 4; r++){
    inv0[r] = 1.0f / __shfl(ls0, q*4 + r, 64);
    inv1[r] = 1.0f / __shfl(ls1, q*4 + r, 64);
  }

  u16* ao = attnout + ((size_t)(b*NPTS + n0))*DH + h*DHEAD;
  #pragma unroll
  for (int dt = 0; dt < 4; dt++)
    #pragma unroll
    for (int r = 0; r < 4; r++){
      ao[(size_t)(q*4 + r)*DH + dt*16 + c] =
          f2bf(fmaxf(O0[dt][r]*inv0[r], 0.f));
      ao[(size_t)(16 + q*4 + r)*DH + dt*16 + c] =
          f2bf(fmaxf(O1[dt][r]*inv1[r], 0.f));
    }
}

// ---------------------------------------------------------------------------
// K4: proj MFMA GEMM (R13-proven): LDS 2-phase pipeline, 64x64 tiles,
// 1024 blocks = 4 blocks/CU, XCD swizzle, direct fp32 stores.
// ---------------------------------------------------------------------------
__global__ __launch_bounds__(256) void k_proj(
    const u16* __restrict__ attn, const u16* __restrict__ pwb,
    const float* __restrict__ bias, float* __restrict__ out)
{
  __shared__ u16 As[2][2048];          // 64 rows x 32 cols
  __shared__ u16 Bs[2][2048];          // 64 rows x 32 cols

  const int blk = blockIdx.x;          // 1024 blocks, XCD-swizzled
  const int xcd = blk & 7;
  const int idx = blk >> 3;            // 0..127
  const int b    = xcd*4 + (idx >> 5); // 4 b's per XCD
  const int inner = idx & 31;
  const int Nblk = inner >> 2;         // 0..7 (64-wide)
  const int Mblk = inner & 3;          // 4 consecutive share (b,Nblk) B-panel

  const int tid = threadIdx.x, wave = tid >> 6, lane = tid & 63;
  const int wm = wave >> 1, wn = wave & 1;
  const int c = lane & 15, q = lane >> 4;
  const int Mbase = Mblk*64 + wm*32;
  const int Nbase = Nblk*64 + wn*32;

  f32x4 acc[2][2];
  #pragma unroll
  for (int mt = 0; mt < 2; mt++){
    f32x4 bi;
    #pragma unroll
    for (int r = 0; r < 4; r++) bi[r] = bias[Mbase + mt*16 + q*4 + r];
    #pragma unroll
    for (int nt = 0; nt < 2; nt++) acc[mt][nt] = bi;
  }

  const u16* aT = pwb + (size_t)(Mblk*64)*DH;
  const u16* bT = attn + ((size_t)b*NPTS + Nblk*64)*DH;

  const int srow = lane >> 2, scol = (lane & 3)*8;

  auto STAGE = [&](int buf, int kc){
    // A: 4 chunks of 16 rows, one per wave; B: same.
    gld16(aT + (size_t)(wave*16 + srow)*DH + kc + scol, &As[buf][wave*512]);
    gld16(bT + (size_t)(wave*16 + srow)*DH + kc + scol, &Bs[buf][wave*512]);
  };

  STAGE(0, 0);
  __syncthreads();

  int cur = 0;
  #pragma unroll 2
  for (int ks = 0; ks < 16; ks++){
    if (ks < 15) STAGE(cur^1, (ks+1)*32);
    bf16x8 aW[2], bA[2];
    #pragma unroll
    for (int mt = 0; mt < 2; mt++)
      aW[mt] = *(const bf16x8*)&As[cur][(wm*32 + mt*16 + c)*32 + q*8];
    #pragma unroll
    for (int nt = 0; nt < 2; nt++)
      bA[nt] = *(const bf16x8*)&Bs[cur][(wn*32 + nt*16 + c)*32 + q*8];
    #pragma unroll
    for (int mt = 0; mt < 2; mt++)
      #pragma unroll
      for (int nt = 0; nt < 2; nt++)
        acc[mt][nt] = __builtin_amdgcn_mfma_f32_16x16x32_bf16(
            aW[mt], bA[nt], acc[mt][nt], 0, 0, 0);
    __syncthreads();
    cur ^= 1;
  }

  #pragma unroll
  for (int mt = 0; mt < 2; mt++){
    #pragma unroll
    for (int nt = 0; nt < 2; nt++){
      const int n = Nbase + nt*16 + c;
      #pragma unroll
      for (int r = 0; r < 4; r++){
        int o = Mbase + mt*16 + q*4 + r;
        out[((size_t)b*DIM + o)*NPTS + n] = acc[mt][nt][r];
      }
    }
  }
}

// ---------------------------------------------------------------------------
extern "C" void kernel_launch(void* const* d_in, const int* in_sizes, int n_in,
                              void* d_out, int out_size, void* d_ws, size_t ws_size,
                              hipStream_t stream)
{
  const float* x     = (const float*)d_in[0];
  const float* qkv_w = (const float*)d_in[1];
  const float* qkv_s = (const float*)d_in[2];
  const float* qkv_b = (const float*)d_in[3];
  const float* dw_w  = (const float*)d_in[4];
  const float* dw_s  = (const float*)d_in[5];
  const float* dw_b  = (const float*)d_in[6];
  const float* ab    = (const float*)d_in[7];
  const float* pw    = (const float*)d_in[8];
  const float* ps    = (const float*)d_in[9];
  const float* pb    = (const float*)d_in[10];
  const int* bidx    = (const int*)d_in[11];

  char* ws = (char*)d_ws;
  u16*   qfb   = (u16*)  (ws);                  //  4 MB (B,128,512) bf16
  u16*   kb    = (u16*)  (ws + ( 8u << 20));    //  4 MB (B,8,512,16) bf16
  u16*   vb    = (u16*)  (ws + (12u << 20));    // 16 MB (B,512,512) bf16 [b][d][p]
  u16*   attn  = (u16*)  (ws + (28u << 20));    // 16 MB (B,512,512) bf16 rows [n][dh]
  u32*   biasb = (u32*)  (ws + (44u << 20));    //  4 MB (8,32,32,64,4) bf16 S^T layout
  u32*   wqb   = (u32*)  (ws + (48u << 20));    // 384 KB (768,256) bf16
  u32*   pwb   = (u32*)  (ws + (49u << 20));    // 256 KB (256,512) bf16
  u16*   xbt   = (u16*)  (ws + (50u << 20));    //  8 MB (B,512,256) bf16 rows

  k_pre <<<dim3(2688),     256, 0, stream>>>(qkv_w, qkv_s, pw, ps, wqb, pwb,
                                             x, xbt, ab, bidx, biasb);
  k_qkv <<<dim3(1536),     256, 0, stream>>>(xbt, (const u16*)wqb, qkv_b, qfb, kb, vb);
  k_attn<<<dim3(256, 4),   256, 0, stream>>>(qfb, kb, vb, (const u16*)biasb,
                                             dw_w, dw_s, dw_b, attn);
  k_proj<<<dim3(1024),     256, 0, stream>>>(attn, (const u16*)pwb, pb, (float*)d_out);
}